// Round 6
// baseline (134.554 us; speedup 1.0000x reference)
//
#include <hip/hip_runtime.h>

#define N 8192
#define D 512
#define NB (N / 128)          // 64 row blocks (128 rows)
#define NSB 32                // 32 col superblocks (256 cols)
#define NBRICKS (NSB * (NSB + 1))   // 1056 triangular bricks
#define MARGIN 0.3f

typedef __attribute__((ext_vector_type(8))) short bf16x8;   // 8 bf16 = 4 VGPRs
typedef __attribute__((ext_vector_type(4))) float f32x4;    // MFMA accumulator

// round-to-nearest-even fp32 -> bf16
__device__ __forceinline__ unsigned short f2bf(float f) {
    unsigned int u = __float_as_uint(f);
    u += 0x7fffu + ((u >> 16) & 1u);
    return (unsigned short)(u >> 16);
}

// async global->LDS, 16B per lane; LDS dest = wave-uniform base + lane*16.
__device__ __forceinline__ void gload_lds16(const void* g, void* l) {
    __builtin_amdgcn_global_load_lds(
        (const __attribute__((address_space(1))) void*)g,
        (__attribute__((address_space(3))) void*)l,
        16, 0, 0);
}

// Kernel 1: per-row fp32 sum-of-squares (exact) + bf16 cast + accumulator init.
__global__ void prep_kernel(const float* __restrict__ x,
                            unsigned short* __restrict__ xb,
                            float* __restrict__ sq,
                            unsigned int* __restrict__ apU,
                            unsigned int* __restrict__ anU,
                            int* __restrict__ cnt) {
    if (blockIdx.x == 0 && threadIdx.x == 0) cnt[0] = 0;
    int w = threadIdx.x >> 6, lane = threadIdx.x & 63;
    int row = blockIdx.x * 4 + w;
    const float4* p = (const float4*)(x + (size_t)row * D) + lane * 2;
    float4 v0 = p[0], v1 = p[1];
    float s = v0.x * v0.x + v0.y * v0.y + v0.z * v0.z + v0.w * v0.w
            + v1.x * v1.x + v1.y * v1.y + v1.z * v1.z + v1.w * v1.w;
    bf16x8 pk;
    pk[0] = (short)f2bf(v0.x); pk[1] = (short)f2bf(v0.y);
    pk[2] = (short)f2bf(v0.z); pk[3] = (short)f2bf(v0.w);
    pk[4] = (short)f2bf(v1.x); pk[5] = (short)f2bf(v1.y);
    pk[6] = (short)f2bf(v1.z); pk[7] = (short)f2bf(v1.w);
    *(bf16x8*)(xb + (size_t)row * D + lane * 8) = pk;
    #pragma unroll
    for (int o = 32; o > 0; o >>= 1) s += __shfl_xor(s, o);
    if (lane == 0) {
        sq[row] = s;
        apU[row] = 0u;                 // max-d^2 accumulator (d^2 clamped >= 0)
        anU[row] = 0x7f800000u;        // min-d^2 accumulator (+inf)
    }
}

// Kernel 2: 128x256 brick, triangular grid; 4 waves of 64x128 (4tm x 8tn MFMA).
// d^2-space selection; one uint atomicMax/Min per row/col per brick; the LAST
// brick (device counter) finalizes: sqrt+relu+mean -> out[0].
__global__ __launch_bounds__(256, 2)
void gemm_kernel(const unsigned short* __restrict__ xb,
                 const float* __restrict__ sq,
                 const int* __restrict__ tgt,
                 unsigned int* __restrict__ apU,
                 unsigned int* __restrict__ anU,
                 int* __restrict__ cnt,
                 float* __restrict__ out) {
    __shared__ __align__(16) char smem_raw[55296];          // tiles(48K) / overlays(54K)
    __shared__ float sqI[128], sqJ[256];
    __shared__ int tI[128], tJ[256];
    __shared__ float ss[4];
    __shared__ int amLast;
    unsigned short* Asm = (unsigned short*)smem_raw;        // [128][64] bf16 swizzled
    unsigned short* Bsm = Asm + 128 * 64;                   // [256][64] bf16 swizzled
    float* redAp = (float*)smem_raw;                        // [128][34]
    float* redAn = redAp + 128 * 34;
    float* colAp = redAn + 128 * 34;                        // [256][10]
    float* colAn = colAp + 256 * 10;                        // total 55296 B

    const int tid = threadIdx.x;
    const int w = tid >> 6, lane = tid & 63, q = lane >> 4, c = lane & 15;
    const int wm = w & 1, wn = w >> 1;                      // 64-row x 128-col per wave

    // decode brick: col-superblock bj2 has 2*bj2+2 row-blocks
    int rem = blockIdx.x, bj2 = 0;
    while (rem >= 2 * bj2 + 2) { rem -= 2 * bj2 + 2; bj2++; }
    const int bi = rem;
    const int rowBase = bi * 128, colBase = bj2 * 256;

    if (tid < 128) { sqI[tid] = sq[rowBase + tid]; tI[tid] = tgt[rowBase + tid]; }
    sqJ[tid] = sq[colBase + tid]; tJ[tid] = tgt[colBase + tid];

    // Hoisted staging pointers: 4 A-chunks + 8 B-chunks per thread per k0.
    const unsigned short* aSrc[4]; unsigned short* aDst[4];
    const unsigned short* bSrc[8]; unsigned short* bDst[8];
    #pragma unroll
    for (int s = 0; s < 4; s++) {
        int p = s * 256 + tid, r = p >> 3, kc = (p & 7) ^ (r & 7);
        aSrc[s] = xb + (size_t)(rowBase + r) * D + kc * 8;
        aDst[s] = Asm + p * 8;
    }
    #pragma unroll
    for (int s = 0; s < 8; s++) {
        int p = s * 256 + tid, r = p >> 3, kc = (p & 7) ^ (r & 7);
        bSrc[s] = xb + (size_t)(colBase + r) * D + kc * 8;
        bDst[s] = Bsm + p * 8;
    }

    f32x4 acc[4][8] = {};

    for (int k0 = 0; k0 < D; k0 += 64) {
        #pragma unroll
        for (int s = 0; s < 4; s++) gload_lds16(aSrc[s] + k0, aDst[s]);
        #pragma unroll
        for (int s = 0; s < 8; s++) gload_lds16(bSrc[s] + k0, bDst[s]);
        __syncthreads();
        #pragma unroll
        for (int kk = 0; kk < 64; kk += 32) {
            const int kx = ((kk >> 3) + q) ^ (c & 7);       // swizzled chunk
            bf16x8 af[4], bfr[8];
            #pragma unroll
            for (int t = 0; t < 4; t++)
                af[t] = *(const bf16x8*)(Asm + (wm * 64 + t * 16 + c) * 64 + kx * 8);
            #pragma unroll
            for (int t = 0; t < 8; t++)
                bfr[t] = *(const bf16x8*)(Bsm + (wn * 128 + t * 16 + c) * 64 + kx * 8);
            #pragma unroll
            for (int tm = 0; tm < 4; tm++)
                #pragma unroll
                for (int tn = 0; tn < 8; tn++)
                    acc[tm][tn] = __builtin_amdgcn_mfma_f32_16x16x32_bf16(
                        af[tm], bfr[tn], acc[tm][tn], 0, 0, 0);
        }
        __syncthreads();
    }

    // Epilogue. C/D layout: col = lane&15 (per tn), row = q*4 + reg (per tm).
    float sjc[8]; int tj8[8];
    #pragma unroll
    for (int tn = 0; tn < 8; tn++) {
        int col_l = wn * 128 + tn * 16 + c;
        sjc[tn] = sqJ[col_l]; tj8[tn] = tJ[col_l];
    }
    float apc[8], anc[8];
    #pragma unroll
    for (int tn = 0; tn < 8; tn++) { apc[tn] = -1e30f; anc[tn] = 1e30f; }
    #pragma unroll
    for (int tm = 0; tm < 4; tm++) {
        #pragma unroll
        for (int r = 0; r < 4; r++) {
            int row_l = wm * 64 + tm * 16 + q * 4 + r;
            float si = sqI[row_l]; int ti = tI[row_l];
            float rp = -1e30f, rn = 1e30f;
            #pragma unroll
            for (int tn = 0; tn < 8; tn++) {
                float p = acc[tm][tn][r];
                bool same = (ti == tj8[tn]);
                float rk = fmaf(-2.0f, p, sjc[tn]);         // row-side key
                float ck = fmaf(-2.0f, p, si);              // col-side key
                rp = fmaxf(rp, same ? rk : -1e30f);
                rn = fminf(rn, same ? 1e30f : rk);
                apc[tn] = fmaxf(apc[tn], same ? ck : -1e30f);
                anc[tn] = fminf(anc[tn], same ? 1e30f : ck);
            }
            redAp[row_l * 34 + wn * 16 + c] = rp;           // tiles dead (post-barrier)
            redAn[row_l * 34 + wn * 16 + c] = rn;
        }
    }
    #pragma unroll
    for (int tn = 0; tn < 8; tn++) {                        // disjoint LDS region
        int col_l = wn * 128 + tn * 16 + c;
        colAp[col_l * 10 + wm * 4 + q] = apc[tn];
        colAn[col_l * 10 + wm * 4 + q] = anc[tn];
    }
    __syncthreads();                                        // ONE epilogue barrier
    if (tid < 128) {                                        // row finalize
        float ap = -1e30f, an = 1e30f;
        #pragma unroll 8
        for (int u = 0; u < 32; u++) {
            ap = fmaxf(ap, redAp[tid * 34 + u]);
            an = fminf(an, redAn[tid * 34 + u]);
        }
        float apd = fmaxf(sqI[tid] + ap, 0.0f);
        float and_ = fmaxf(sqI[tid] + an, 0.0f);
        atomicMax(&apU[rowBase + tid], __float_as_uint(apd));
        atomicMin(&anU[rowBase + tid], __float_as_uint(and_));
    }
    {                                                       // col finalize (no barrier
        float ap = -1e30f, an = 1e30f;                      //  needed: read-only phase)
        #pragma unroll
        for (int u = 0; u < 8; u++) {
            ap = fmaxf(ap, colAp[tid * 10 + u]);
            an = fminf(an, colAn[tid * 10 + u]);
        }
        float apd = fmaxf(sqJ[tid] + ap, 0.0f);
        float and_ = fmaxf(sqJ[tid] + an, 0.0f);
        atomicMax(&apU[colBase + tid], __float_as_uint(apd));
        atomicMin(&anU[colBase + tid], __float_as_uint(and_));
    }
    // Brick-done counter. The barrier's vmcnt(0) drain guarantees this block's
    // atomics are complete (device-visible) before the increment.
    __syncthreads();
    if (tid == 0) {
        __threadfence();
        amLast = (atomicAdd(cnt, 1) == NBRICKS - 1);
    }
    __syncthreads();
    if (amLast) {
        // Last brick: all apU/anU finalized. Read via idempotent device-scope
        // RMWs (cross-XCD safe), sqrt+relu, mean.
        float local = 0.0f;
        #pragma unroll 4
        for (int i = 0; i < N / 256; i++) {
            int row = i * 256 + tid;
            float ap = __uint_as_float(atomicMax(&apU[row], 0u));
            float an = __uint_as_float(atomicMin(&anU[row], 0x7f800000u));
            float dap = sqrtf(fmaxf(ap, 1e-12f));
            float dan = sqrtf(fmaxf(an, 1e-12f));
            local += fmaxf(dap - dan + MARGIN, 0.0f);
        }
        #pragma unroll
        for (int o = 32; o > 0; o >>= 1) local += __shfl_xor(local, o);
        if ((tid & 63) == 0) ss[tid >> 6] = local;
        __syncthreads();
        if (tid == 0) out[0] = (ss[0] + ss[1] + ss[2] + ss[3]) * (1.0f / (float)N);
    }
}

extern "C" void kernel_launch(void* const* d_in, const int* in_sizes, int n_in,
                              void* d_out, int out_size, void* d_ws, size_t ws_size,
                              hipStream_t stream) {
    const float* x  = (const float*)d_in[0];
    const int* tgt  = (const int*)d_in[1];
    float* out      = (float*)d_out;

    char* ws = (char*)d_ws;
    unsigned short* xb = (unsigned short*)ws;                       // 8 MB bf16 X
    float* sq   = (float*)(ws + (size_t)N * D * 2);                 // 32 KB
    unsigned int* apU = (unsigned int*)(sq + N);                    // 32 KB
    unsigned int* anU = apU + N;                                    // 32 KB
    int* cnt = (int*)(anU + N);

    prep_kernel<<<N / 4, 256, 0, stream>>>(x, xb, sq, apU, anU, cnt);
    gemm_kernel<<<NBRICKS, 256, 0, stream>>>(xb, sq, tgt, apU, anU, cnt, out);
}